// Round 8
// baseline (693.668 us; speedup 1.0000x reference)
//
#include <hip/hip_runtime.h>

#define LN_EPS 1e-5f

typedef __attribute__((ext_vector_type(8))) short short8v;
typedef __attribute__((ext_vector_type(4))) float f32x4;

__device__ __forceinline__ unsigned short f2bf(float f) {
  union { float f; unsigned u; } v; v.f = f;
  unsigned r = v.u + 0x7FFFu + ((v.u >> 16) & 1u);
  return (unsigned short)(r >> 16);
}
__device__ __forceinline__ float bf2f(unsigned short b) {
  union { unsigned u; float f; } v; v.u = ((unsigned)b) << 16;
  return v.f;
}
__device__ __forceinline__ float lo16(unsigned v) { return bf2f((unsigned short)(v & 0xffff)); }
__device__ __forceinline__ float hi16(unsigned v) { return bf2f((unsigned short)(v >> 16)); }

__device__ __forceinline__ short8v cvt8(float4 a, float4 b) {
  short8v r;
  r[0] = (short)f2bf(a.x); r[1] = (short)f2bf(a.y);
  r[2] = (short)f2bf(a.z); r[3] = (short)f2bf(a.w);
  r[4] = (short)f2bf(b.x); r[5] = (short)f2bf(b.y);
  r[6] = (short)f2bf(b.z); r[7] = (short)f2bf(b.w);
  return r;
}

// ---------------- prep: zero [agg1|agg2|deg1|deg2] + cvt weights to bf16 ----------------

__global__ __launch_bounds__(256) void k_prep(
    int4* __restrict__ z, int nz4,
    const float* __restrict__ wa, unsigned short* __restrict__ oa, int na,
    const float* __restrict__ wb, unsigned short* __restrict__ ob, int nb,
    const float* __restrict__ wc, unsigned short* __restrict__ oc, int nc,
    const float* __restrict__ wd, unsigned short* __restrict__ od, int nd) {
  int i = blockIdx.x * 256 + threadIdx.x;
  if (i < nz4) { z[i] = make_int4(0, 0, 0, 0); return; }
  i -= nz4;
  if (i < na) { oa[i] = f2bf(wa[i]); return; }
  i -= na;
  if (i < nb) { ob[i] = f2bf(wb[i]); return; }
  i -= nb;
  if (i < nc) { oc[i] = f2bf(wc[i]); return; }
  i -= nc;
  if (i < nd) { od[i] = f2bf(wd[i]); }
}

// ---------------- scatter1: edge-parallel fp32 row-add, x (F=128) ----------------
// One wave per 64-edge chunk; per edge: wave-coalesced 128-float add (2 atomics/lane).

__global__ __launch_bounds__(256) void k_scatter1(
    const float* __restrict__ X, const int* __restrict__ src,
    const int* __restrict__ dst, int E,
    float* __restrict__ agg, float* __restrict__ deg) {
  const int wid = blockIdx.x * 4 + (threadIdx.x >> 6);
  const int lane = threadIdx.x & 63;
  const int j0 = wid * 64;
  if (j0 >= E) return;
  const int e = j0 + lane;
  int sv = 0, dv = 0;
  if (e < E) {
    sv = src[e];
    dv = dst[e];
    atomicAdd(&deg[dv], 1.0f);
  }
  const int n = min(64, E - j0);
  const int c2 = lane * 2;
#pragma unroll 4
  for (int t = 0; t < n; ++t) {
    int s = __shfl(sv, t), d = __shfl(dv, t);
    float2 v = *(const float2*)(X + (size_t)s * 128 + c2);
    atomicAdd(&agg[(size_t)d * 128 + c2], v.x);
    atomicAdd(&agg[(size_t)d * 128 + c2 + 1], v.y);
  }
}

// ---------------- scatter2: edge-parallel fp32 row-add, h bf16 (F=256) ----------------

__global__ __launch_bounds__(256) void k_scatter2(
    const unsigned short* __restrict__ H, const int* __restrict__ src,
    const int* __restrict__ dst, int E,
    float* __restrict__ agg, float* __restrict__ deg) {
  const int wid = blockIdx.x * 4 + (threadIdx.x >> 6);
  const int lane = threadIdx.x & 63;
  const int j0 = wid * 64;
  if (j0 >= E) return;
  const int e = j0 + lane;
  int sv = 0, dv = 0;
  if (e < E) {
    sv = src[e];
    dv = dst[e];
    atomicAdd(&deg[dv], 1.0f);
  }
  const int n = min(64, E - j0);
  const int c4 = lane * 4;
#pragma unroll 2
  for (int t = 0; t < n; ++t) {
    int s = __shfl(sv, t), d = __shfl(dv, t);
    uint2 v = *(const uint2*)(H + (size_t)s * 256 + c4);
    float* ap = agg + (size_t)d * 256 + c4;
    atomicAdd(ap + 0, lo16(v.x));
    atomicAdd(ap + 1, hi16(v.x));
    atomicAdd(ap + 2, lo16(v.y));
    atomicAdd(ap + 3, hi16(v.y));
  }
}

// ---------------- GEMM1: h = relu(x@Ws^T + (agg1/deg)@Wn^T + b), bf16 out + stat partials --
// M x 256, K=128, BN=64. 4 waves x 16 rows. B bf16 in registers; A fp32->bf16 in-kernel.

__global__ __launch_bounds__(256) void k_gemm1(
    const float* __restrict__ X, const float* __restrict__ AGG,
    const float* __restrict__ DEG,
    const unsigned short* __restrict__ B0, const unsigned short* __restrict__ B1,
    const float* __restrict__ bias, unsigned short* __restrict__ H, int M,
    float* __restrict__ part1, float* __restrict__ part2) {
  constexpr int K = 128, N = 256;
  const int lane = threadIdx.x & 63;
  const int wv = threadIdx.x >> 6;
  const int r16 = lane & 15, hi = lane >> 4;
  const int n0 = blockIdx.x * 64;
  const int m0 = blockIdx.y * 64 + wv * 16;
  int arow = m0 + r16;
  if (arow >= M) arow = M - 1;
  const int koff = hi * 8;

  short8v bf[2][4][4];  // [src][colblock j][kstep t]
#pragma unroll
  for (int s = 0; s < 2; ++s) {
    const unsigned short* B = s ? B1 : B0;
#pragma unroll
    for (int j = 0; j < 4; ++j) {
      const unsigned short* bp = B + (size_t)(n0 + j * 16 + r16) * K + koff;
#pragma unroll
      for (int t = 0; t < 4; ++t) bf[s][j][t] = *(const short8v*)(bp + t * 32);
    }
  }

  f32x4 acc[4];
#pragma unroll
  for (int j = 0; j < 4; ++j) acc[j] = f32x4{0.f, 0.f, 0.f, 0.f};

  const float* a0p = X + (size_t)arow * K + koff;
  const float* a1p = AGG + (size_t)arow * K + koff;
  const float idg = 1.f / fmaxf(DEG[arow], 1.f);
#pragma unroll
  for (int t = 0; t < 4; ++t) {
    short8v a0 = cvt8(*(const float4*)(a0p + t * 32), *(const float4*)(a0p + t * 32 + 4));
    float4 u0 = *(const float4*)(a1p + t * 32);
    float4 u1 = *(const float4*)(a1p + t * 32 + 4);
    u0.x *= idg; u0.y *= idg; u0.z *= idg; u0.w *= idg;
    u1.x *= idg; u1.y *= idg; u1.z *= idg; u1.w *= idg;
    short8v a1 = cvt8(u0, u1);
#pragma unroll
    for (int j = 0; j < 4; ++j)
      acc[j] = __builtin_amdgcn_mfma_f32_16x16x32_bf16(a0, bf[0][j][t], acc[j], 0, 0, 0);
#pragma unroll
    for (int j = 0; j < 4; ++j)
      acc[j] = __builtin_amdgcn_mfma_f32_16x16x32_bf16(a1, bf[1][j][t], acc[j], 0, 0, 0);
  }

  float s1 = 0.f, s2 = 0.f;
#pragma unroll
  for (int j = 0; j < 4; ++j) {
    const int col = n0 + j * 16 + r16;
    const float bj = bias[col];
#pragma unroll
    for (int r = 0; r < 4; ++r) {
      const int m = m0 + hi * 4 + r;
      if (m < M) {
        float c = fmaxf(acc[j][r] + bj, 0.f);
        s1 += c;
        s2 += c * c;
        H[(size_t)m * N + col] = f2bf(c);
      }
    }
  }

#pragma unroll
  for (int o = 32; o > 0; o >>= 1) {
    s1 += __shfl_down(s1, o);
    s2 += __shfl_down(s2, o);
  }
  __shared__ float l1[4], l2[4];
  if (lane == 0) { l1[wv] = s1; l2[wv] = s2; }
  __syncthreads();
  if (threadIdx.x == 0) {
    const int bid = blockIdx.y * gridDim.x + blockIdx.x;
    part1[bid] = l1[0] + l1[1] + l1[2] + l1[3];
    part2[bid] = l2[0] + l2[1] + l2[2] + l2[3];
  }
}

// ---------------- GEMM2: out = inv*(h@Ws^T + (agg2/deg)@Wn^T) - inv*mu*(sWs + g*sWn) + b --
// LN affine applied algebraically in the epilogue; stats reduced per-block from partials.
// M x 64, K=256, BN=16.

__global__ __launch_bounds__(256) void k_gemm2(
    const unsigned short* __restrict__ H, const float* __restrict__ AGG,
    const float* __restrict__ DEG,
    const unsigned short* __restrict__ B0, const unsigned short* __restrict__ B1,
    const float* __restrict__ bias, float* __restrict__ C, int M,
    const float* __restrict__ p1, const float* __restrict__ p2, int nPart,
    float invN) {
  constexpr int K = 256, N = 64;
  const int lane = threadIdx.x & 63;
  const int wv = threadIdx.x >> 6;
  const int r16 = lane & 15, hi = lane >> 4;
  const int n0 = blockIdx.x * 16;
  const int m0 = blockIdx.y * 64 + wv * 16;
  int arow = m0 + r16;
  if (arow >= M) arow = M - 1;
  const int koff = hi * 8;

  // block-redundant LN stats reduce (part written by gemm1, prior launch => visible)
  __shared__ float red1[4], red2[4];
  __shared__ float s_mu, s_inv;
  {
    float s1 = 0.f, s2 = 0.f;
    for (int i = threadIdx.x; i < nPart; i += 256) { s1 += p1[i]; s2 += p2[i]; }
#pragma unroll
    for (int o = 32; o > 0; o >>= 1) {
      s1 += __shfl_down(s1, o);
      s2 += __shfl_down(s2, o);
    }
    if (lane == 0) { red1[wv] = s1; red2[wv] = s2; }
    __syncthreads();
    if (threadIdx.x == 0) {
      float t1 = red1[0] + red1[1] + red1[2] + red1[3];
      float t2 = red2[0] + red2[1] + red2[2] + red2[3];
      float mu = t1 * invN;
      float var = t2 * invN - mu * mu;
      s_mu = mu;
      s_inv = 1.f / sqrtf(var + LN_EPS);
    }
    __syncthreads();
  }
  const float mu = s_mu, inv = s_inv;

  // B frags (bf16) + per-column weight row-sums for the mu-correction
  short8v bfr[2][8];
  float sB0 = 0.f, sB1 = 0.f;
#pragma unroll
  for (int s = 0; s < 2; ++s) {
    const unsigned short* bp = (s ? B1 : B0) + (size_t)(n0 + r16) * K + koff;
#pragma unroll
    for (int t = 0; t < 8; ++t) {
      short8v f = *(const short8v*)(bp + t * 32);
      bfr[s][t] = f;
      float ss = 0.f;
#pragma unroll
      for (int i = 0; i < 8; ++i) ss += bf2f((unsigned short)f[i]);
      if (s) sB1 += ss; else sB0 += ss;
    }
  }
  // sum across the 4 hi-groups (lanes sharing r16)
  sB0 += __shfl_xor(sB0, 16); sB0 += __shfl_xor(sB0, 32);
  sB1 += __shfl_xor(sB1, 16); sB1 += __shfl_xor(sB1, 32);

  f32x4 acc = f32x4{0.f, 0.f, 0.f, 0.f};
  const unsigned short* a0p = H + (size_t)arow * K + koff;
  const float* a1p = AGG + (size_t)arow * K + koff;
  const float idg = 1.f / fmaxf(DEG[arow], 1.f);
#pragma unroll
  for (int t = 0; t < 8; ++t) {
    short8v a0 = *(const short8v*)(a0p + t * 32);
    float4 u0 = *(const float4*)(a1p + t * 32);
    float4 u1 = *(const float4*)(a1p + t * 32 + 4);
    u0.x *= idg; u0.y *= idg; u0.z *= idg; u0.w *= idg;
    u1.x *= idg; u1.y *= idg; u1.z *= idg; u1.w *= idg;
    short8v a1 = cvt8(u0, u1);
    acc = __builtin_amdgcn_mfma_f32_16x16x32_bf16(a0, bfr[0][t], acc, 0, 0, 0);
    acc = __builtin_amdgcn_mfma_f32_16x16x32_bf16(a1, bfr[1][t], acc, 0, 0, 0);
  }

  const int col = n0 + r16;
  const float bj = bias[col];
#pragma unroll
  for (int r = 0; r < 4; ++r) {
    const int m = m0 + hi * 4 + r;
    if (m < M) {
      const float g = (DEG[m] > 0.5f) ? 1.f : 0.f;
      C[(size_t)m * N + col] = inv * acc[r] - inv * mu * (sB0 + g * sB1) + bj;
    }
  }
}

// ---------------- launch ----------------

extern "C" void kernel_launch(void* const* d_in, const int* in_sizes, int n_in,
                              void* d_out, int out_size, void* d_ws, size_t ws_size,
                              hipStream_t stream) {
  const float* x   = (const float*)d_in[0];
  const float* Ws1 = (const float*)d_in[1];
  const float* Wn1 = (const float*)d_in[2];
  const float* b1  = (const float*)d_in[3];
  const float* Ws2 = (const float*)d_in[4];
  const float* Wn2 = (const float*)d_in[5];
  const float* b2  = (const float*)d_in[6];
  const int* src1  = (const int*)d_in[7];
  const int* dst1  = (const int*)d_in[8];
  const int* src2  = (const int*)d_in[9];
  const int* dst2  = (const int*)d_in[10];

  const int E1 = in_sizes[7];
  const int E2 = in_sizes[9];
  const int N1 = 20000, N2 = 4000;
  const int FIN = 128, FH = 256, FOUT = 64;

  char* w = (char*)d_ws;
  auto alloc = [&](size_t bytes) {
    char* p = w;
    w += (bytes + 255) & ~(size_t)255;
    return p;
  };
  // contiguous zero region: agg1 | agg2 | deg1 | deg2
  const size_t zFloats = (size_t)N1 * FIN + (size_t)N2 * FH + N1 + N2;
  float* agg1 = (float*)alloc(zFloats * 4);
  float* agg2 = agg1 + (size_t)N1 * FIN;
  float* deg1 = agg2 + (size_t)N2 * FH;
  float* deg2 = deg1 + N1;
  unsigned short* hbf  = (unsigned short*)alloc((size_t)N1 * FH * 2);
  unsigned short* w1sb = (unsigned short*)alloc((size_t)FH * FIN * 2);
  unsigned short* w1nb = (unsigned short*)alloc((size_t)FH * FIN * 2);
  unsigned short* w2sb = (unsigned short*)alloc((size_t)FOUT * FH * 2);
  unsigned short* w2nb = (unsigned short*)alloc((size_t)FOUT * FH * 2);
  const int nBlk1 = 4 * ((N1 + 63) / 64);  // gemm1 grid = (4, 313)
  float* part1 = (float*)alloc((size_t)nBlk1 * 4);
  float* part2 = (float*)alloc((size_t)nBlk1 * 4);

  // 1) prep: zero aggs/degs + weight bf16 cvt
  {
    const int nz4 = (int)(zFloats / 4);
    const int na = FH * FIN, nc = FOUT * FH;
    const int total = nz4 + 2 * na + 2 * nc;
    k_prep<<<(total + 255) / 256, 256, 0, stream>>>(
        (int4*)agg1, nz4, Ws1, w1sb, na, Wn1, w1nb, na, Ws2, w2sb, nc, Wn2, w2nb, nc);
  }

  // 2) scatter layer-1 edges (fp32 x rows -> agg1, deg1)
  {
    const int chunks = (E1 + 63) / 64;
    k_scatter1<<<(chunks + 3) / 4, 256, 0, stream>>>(x, src1, dst1, E1, agg1, deg1);
  }

  // 3) gemm1 (+ LN stat partials)
  {
    dim3 g(FH / 64, (N1 + 63) / 64);
    k_gemm1<<<g, 256, 0, stream>>>(x, agg1, deg1, w1sb, w1nb, b1, hbf, N1, part1, part2);
  }

  // 4) scatter layer-2 edges (bf16 h rows -> agg2, deg2)
  {
    const int chunks = (E2 + 63) / 64;
    k_scatter2<<<(chunks + 3) / 4, 256, 0, stream>>>(hbf, src2, dst2, E2, agg2, deg2);
  }

  // 5) gemm2 (LN affine folded into epilogue)
  {
    dim3 g(FOUT / 16, (N2 + 63) / 64);
    k_gemm2<<<g, 256, 0, stream>>>(hbf, agg2, deg2, w2sb, w2nb, b2, (float*)d_out, N2,
                                   part1, part2, nBlk1,
                                   1.f / ((float)N1 * (float)FH));
  }
}